// Round 1
// baseline (178.084 us; speedup 1.0000x reference)
//
#include <hip/hip_runtime.h>

// Problem constants: x [B=16, C=256, H=128, W=128] f32 (NCHW)
#define BB 16
#define CC 256
#define HH 128
#define WW 128
#define HWSZ (HH * WW)          // 16384
#define BHW (BB * HWSZ)         // 262144
#define TOTAL (BB * CC * HWSZ)  // 67108864

// Kernel 1: channel pool. One thread = one float4 of spatial positions.
// Grid: BHW/4 / 256 = 256 blocks.
__global__ __launch_bounds__(256) void pool_kernel(const float* __restrict__ x,
                                                   float* __restrict__ pmax,
                                                   float* __restrict__ pmean) {
    int tid = blockIdx.x * 256 + threadIdx.x;   // 0 .. BHW/4
    int b   = tid >> 12;                        // / (HWSZ/4 = 4096)
    int hw4 = tid & 4095;
    const float4* xb = (const float4*)x + ((size_t)b << 20) + hw4;  // b*C*HW/4
    float4 v = xb[0];
    float mx0 = v.x, mx1 = v.y, mx2 = v.z, mx3 = v.w;
    float s0 = v.x, s1 = v.y, s2 = v.z, s3 = v.w;
    #pragma unroll 8
    for (int c = 1; c < CC; ++c) {
        float4 u = xb[(size_t)c * (HWSZ / 4)];
        mx0 = fmaxf(mx0, u.x); s0 += u.x;
        mx1 = fmaxf(mx1, u.y); s1 += u.y;
        mx2 = fmaxf(mx2, u.z); s2 += u.z;
        mx3 = fmaxf(mx3, u.w); s3 += u.w;
    }
    const float inv = 1.0f / (float)CC;
    float4 m4 = make_float4(mx0, mx1, mx2, mx3);
    float4 a4 = make_float4(s0 * inv, s1 * inv, s2 * inv, s3 * inv);
    ((float4*)pmax)[tid]  = m4;
    ((float4*)pmean)[tid] = a4;
}

// Kernel 2: 7x7 conv (2 in-ch: [max, mean]) + bias + BN + sigmoid -> att.
// One thread per spatial position. Grid: BHW/256 = 1024 blocks.
__global__ __launch_bounds__(256) void conv_kernel(const float* __restrict__ pmax,
                                                   const float* __restrict__ pmean,
                                                   const float* __restrict__ cw,
                                                   const float* __restrict__ cb,
                                                   const float* __restrict__ g,
                                                   const float* __restrict__ be,
                                                   const float* __restrict__ mu,
                                                   const float* __restrict__ var,
                                                   float* __restrict__ att) {
    __shared__ float w[98];
    __shared__ float sc[2];
    if (threadIdx.x < 98) w[threadIdx.x] = cw[threadIdx.x];
    if (threadIdx.x == 0) {
        float scale = g[0] * rsqrtf(var[0] + 1e-5f);
        sc[0] = scale;
        // final = (conv_sum + cb)*scale + beta - mu*scale
        sc[1] = cb[0] * scale + be[0] - mu[0] * scale;
    }
    __syncthreads();

    int s  = blockIdx.x * 256 + threadIdx.x;    // 0 .. BHW
    int b  = s >> 14;                           // / HWSZ
    int hw = s & (HWSZ - 1);
    int h  = hw >> 7;
    int ww = hw & 127;
    const float* pm = pmax  + (size_t)b * HWSZ;
    const float* pa = pmean + (size_t)b * HWSZ;

    float acc = 0.0f;
    #pragma unroll
    for (int kh = 0; kh < 7; ++kh) {
        int hh = h + kh - 3;
        if ((unsigned)hh < (unsigned)HH) {
            int rowoff = hh << 7;
            #pragma unroll
            for (int kw = 0; kw < 7; ++kw) {
                int wcol = ww + kw - 3;
                if ((unsigned)wcol < (unsigned)WW) {
                    int o = rowoff + wcol;
                    acc = fmaf(w[kh * 7 + kw],      pm[o], acc);
                    acc = fmaf(w[49 + kh * 7 + kw], pa[o], acc);
                }
            }
        }
    }
    float y = fmaf(acc, sc[0], sc[1]);
    att[s] = 1.0f / (1.0f + __expf(-y));
}

// Kernel 3: out = x * att (broadcast over C). Grid-stride, float4.
__global__ __launch_bounds__(256) void mul_kernel(const float* __restrict__ x,
                                                  const float* __restrict__ att,
                                                  float* __restrict__ out,
                                                  int total4) {
    int stride = gridDim.x * 256;
    for (int i = blockIdx.x * 256 + threadIdx.x; i < total4; i += stride) {
        int p   = i >> 12;        // b*C + c  (HWSZ/4 = 4096 float4 per plane)
        int b   = p >> 8;         // / C
        int hw4 = i & 4095;
        float4 a = ((const float4*)att)[(b << 12) + hw4];
        float4 v = ((const float4*)x)[i];
        v.x *= a.x; v.y *= a.y; v.z *= a.z; v.w *= a.w;
        ((float4*)out)[i] = v;
    }
}

extern "C" void kernel_launch(void* const* d_in, const int* in_sizes, int n_in,
                              void* d_out, int out_size, void* d_ws, size_t ws_size,
                              hipStream_t stream) {
    const float* x   = (const float*)d_in[0];
    const float* cw  = (const float*)d_in[1];
    const float* cb  = (const float*)d_in[2];
    const float* g   = (const float*)d_in[3];
    const float* be  = (const float*)d_in[4];
    const float* mu  = (const float*)d_in[5];
    const float* var = (const float*)d_in[6];
    float* out = (float*)d_out;

    float* pmax  = (float*)d_ws;
    float* pmean = pmax + BHW;
    float* att   = pmean + BHW;

    pool_kernel<<<BHW / 4 / 256, 256, 0, stream>>>(x, pmax, pmean);
    conv_kernel<<<BHW / 256, 256, 0, stream>>>(pmax, pmean, cw, cb, g, be, mu, var, att);
    mul_kernel<<<4096, 256, 0, stream>>>(x, att, out, TOTAL / 4);
}

// Round 2
// 171.232 us; speedup vs baseline: 1.0400x; 1.0400x over previous
//
#include <hip/hip_runtime.h>

// Problem constants: x [B=16, C=256, H=128, W=128] f32 (NCHW)
#define BB 16
#define CC 256
#define HH 128
#define WW 128
#define HWSZ (HH * WW)          // 16384
#define HW4 (HWSZ / 4)          // 4096 float4 per plane
#define BHW (BB * HWSZ)         // 262144
#define TOTAL (BB * CC * HWSZ)  // 67108864

// Kernel 1: channel pool, C split 4-way within the block for occupancy.
// Block = 256 threads = 64 spatial float4 positions x 4 channel-chunks (64 ch each).
// Grid = BHW/4/64 = 1024 blocks -> 4 blocks/CU, 16 waves/CU.
__global__ __launch_bounds__(256) void pool_kernel(const float* __restrict__ x,
                                                   float* __restrict__ pmax,
                                                   float* __restrict__ pmean) {
    __shared__ float4 smax[256];
    __shared__ float4 ssum[256];
    int t     = threadIdx.x;
    int pos   = t & 63;         // spatial float4 slot within block
    int chunk = t >> 6;         // 0..3 channel chunk
    int gpos  = blockIdx.x * 64 + pos;      // global float4 index, 0..65535
    int b     = gpos >> 12;                 // / HW4
    int hw4   = gpos & (HW4 - 1);
    // offset = b*C*HW4 + chunk*64*HW4 + hw4
    const float4* xb = (const float4*)x + ((size_t)b << 20) + ((size_t)chunk << 18) + hw4;

    float4 v = xb[0];
    float mx0 = v.x, mx1 = v.y, mx2 = v.z, mx3 = v.w;
    float s0 = v.x, s1 = v.y, s2 = v.z, s3 = v.w;
    #pragma unroll 8
    for (int c = 1; c < 64; ++c) {
        float4 u = xb[(size_t)c << 12];
        mx0 = fmaxf(mx0, u.x); s0 += u.x;
        mx1 = fmaxf(mx1, u.y); s1 += u.y;
        mx2 = fmaxf(mx2, u.z); s2 += u.z;
        mx3 = fmaxf(mx3, u.w); s3 += u.w;
    }
    smax[t] = make_float4(mx0, mx1, mx2, mx3);
    ssum[t] = make_float4(s0, s1, s2, s3);
    __syncthreads();

    if (t < 64) {
        float4 m0 = smax[t],       m1 = smax[t + 64],
               m2 = smax[t + 128], m3 = smax[t + 192];
        float4 a0 = ssum[t],       a1 = ssum[t + 64],
               a2 = ssum[t + 128], a3 = ssum[t + 192];
        float4 m, a;
        m.x = fmaxf(fmaxf(m0.x, m1.x), fmaxf(m2.x, m3.x));
        m.y = fmaxf(fmaxf(m0.y, m1.y), fmaxf(m2.y, m3.y));
        m.z = fmaxf(fmaxf(m0.z, m1.z), fmaxf(m2.z, m3.z));
        m.w = fmaxf(fmaxf(m0.w, m1.w), fmaxf(m2.w, m3.w));
        const float inv = 1.0f / (float)CC;
        a.x = (a0.x + a1.x + a2.x + a3.x) * inv;
        a.y = (a0.y + a1.y + a2.y + a3.y) * inv;
        a.z = (a0.z + a1.z + a2.z + a3.z) * inv;
        a.w = (a0.w + a1.w + a2.w + a3.w) * inv;
        ((float4*)pmax)[gpos]  = m;
        ((float4*)pmean)[gpos] = a;
    }
}

// Kernel 2: 7x7 conv (2 in-ch: [max, mean]) + bias + BN + sigmoid -> att.
// One thread per spatial position. Grid: BHW/256 = 1024 blocks.
__global__ __launch_bounds__(256) void conv_kernel(const float* __restrict__ pmax,
                                                   const float* __restrict__ pmean,
                                                   const float* __restrict__ cw,
                                                   const float* __restrict__ cb,
                                                   const float* __restrict__ g,
                                                   const float* __restrict__ be,
                                                   const float* __restrict__ mu,
                                                   const float* __restrict__ var,
                                                   float* __restrict__ att) {
    __shared__ float w[98];
    __shared__ float sc[2];
    if (threadIdx.x < 98) w[threadIdx.x] = cw[threadIdx.x];
    if (threadIdx.x == 0) {
        float scale = g[0] * rsqrtf(var[0] + 1e-5f);
        sc[0] = scale;
        sc[1] = cb[0] * scale + be[0] - mu[0] * scale;
    }
    __syncthreads();

    int s  = blockIdx.x * 256 + threadIdx.x;    // 0 .. BHW
    int b  = s >> 14;                           // / HWSZ
    int hw = s & (HWSZ - 1);
    int h  = hw >> 7;
    int ww = hw & 127;
    const float* pm = pmax  + (size_t)b * HWSZ;
    const float* pa = pmean + (size_t)b * HWSZ;

    float acc = 0.0f;
    #pragma unroll
    for (int kh = 0; kh < 7; ++kh) {
        int hh = h + kh - 3;
        if ((unsigned)hh < (unsigned)HH) {
            int rowoff = hh << 7;
            #pragma unroll
            for (int kw = 0; kw < 7; ++kw) {
                int wcol = ww + kw - 3;
                if ((unsigned)wcol < (unsigned)WW) {
                    int o = rowoff + wcol;
                    acc = fmaf(w[kh * 7 + kw],      pm[o], acc);
                    acc = fmaf(w[49 + kh * 7 + kw], pa[o], acc);
                }
            }
        }
    }
    float y = fmaf(acc, sc[0], sc[1]);
    att[s] = 1.0f / (1.0f + __expf(-y));
}

// Kernel 3: out = x * att (broadcast over C). Grid-stride, float4.
__global__ __launch_bounds__(256) void mul_kernel(const float* __restrict__ x,
                                                  const float* __restrict__ att,
                                                  float* __restrict__ out,
                                                  int total4) {
    int stride = gridDim.x * 256;
    for (int i = blockIdx.x * 256 + threadIdx.x; i < total4; i += stride) {
        int p   = i >> 12;        // b*C + c
        int b   = p >> 8;         // / C
        int hw4 = i & (HW4 - 1);
        float4 a = ((const float4*)att)[(b << 12) + hw4];
        float4 v = ((const float4*)x)[i];
        v.x *= a.x; v.y *= a.y; v.z *= a.z; v.w *= a.w;
        ((float4*)out)[i] = v;
    }
}

extern "C" void kernel_launch(void* const* d_in, const int* in_sizes, int n_in,
                              void* d_out, int out_size, void* d_ws, size_t ws_size,
                              hipStream_t stream) {
    const float* x   = (const float*)d_in[0];
    const float* cw  = (const float*)d_in[1];
    const float* cb  = (const float*)d_in[2];
    const float* g   = (const float*)d_in[3];
    const float* be  = (const float*)d_in[4];
    const float* mu  = (const float*)d_in[5];
    const float* var = (const float*)d_in[6];
    float* out = (float*)d_out;

    float* pmax  = (float*)d_ws;
    float* pmean = pmax + BHW;
    float* att   = pmean + BHW;

    pool_kernel<<<BHW / 4 / 64, 256, 0, stream>>>(x, pmax, pmean);
    conv_kernel<<<BHW / 256, 256, 0, stream>>>(pmax, pmean, cw, cb, g, be, mu, var, att);
    mul_kernel<<<4096, 256, 0, stream>>>(x, att, out, TOTAL / 4);
}

// Round 3
// 151.645 us; speedup vs baseline: 1.1743x; 1.1292x over previous
//
#include <hip/hip_runtime.h>

// Problem constants: x [B=16, C=256, H=128, W=128] f32 (NCHW)
#define BB 16
#define CC 256
#define HH 128
#define WW 128
#define HWSZ (HH * WW)          // 16384
#define HW4 (HWSZ / 4)          // 4096 float4 per plane
#define BHW (BB * HWSZ)         // 262144
#define TOTAL (BB * CC * HWSZ)  // 67108864

typedef float f32x4 __attribute__((ext_vector_type(4)));

// Kernel 1: channel pool, C split 4-way within the block.
// Block = 256 threads = 64 spatial float4 positions x 4 channel-chunks (64 ch each).
// Grid = 1024 blocks. Loads are TEMPORAL on purpose: they populate L3 so the
// mul kernel's second read of x hits Infinity Cache.
__global__ __launch_bounds__(256) void pool_kernel(const float* __restrict__ x,
                                                   float* __restrict__ pmax,
                                                   float* __restrict__ pmean) {
    __shared__ float4 smax[256];
    __shared__ float4 ssum[256];
    int t     = threadIdx.x;
    int pos   = t & 63;
    int chunk = t >> 6;
    int gpos  = blockIdx.x * 64 + pos;
    int b     = gpos >> 12;
    int hw4   = gpos & (HW4 - 1);
    const float4* xb = (const float4*)x + ((size_t)b << 20) + ((size_t)chunk << 18) + hw4;

    float4 v = xb[0];
    float mx0 = v.x, mx1 = v.y, mx2 = v.z, mx3 = v.w;
    float s0 = v.x, s1 = v.y, s2 = v.z, s3 = v.w;
    #pragma unroll 8
    for (int c = 1; c < 64; ++c) {
        float4 u = xb[(size_t)c << 12];
        mx0 = fmaxf(mx0, u.x); s0 += u.x;
        mx1 = fmaxf(mx1, u.y); s1 += u.y;
        mx2 = fmaxf(mx2, u.z); s2 += u.z;
        mx3 = fmaxf(mx3, u.w); s3 += u.w;
    }
    smax[t] = make_float4(mx0, mx1, mx2, mx3);
    ssum[t] = make_float4(s0, s1, s2, s3);
    __syncthreads();

    if (t < 64) {
        float4 m0 = smax[t],       m1 = smax[t + 64],
               m2 = smax[t + 128], m3 = smax[t + 192];
        float4 a0 = ssum[t],       a1 = ssum[t + 64],
               a2 = ssum[t + 128], a3 = ssum[t + 192];
        float4 m, a;
        m.x = fmaxf(fmaxf(m0.x, m1.x), fmaxf(m2.x, m3.x));
        m.y = fmaxf(fmaxf(m0.y, m1.y), fmaxf(m2.y, m3.y));
        m.z = fmaxf(fmaxf(m0.z, m1.z), fmaxf(m2.z, m3.z));
        m.w = fmaxf(fmaxf(m0.w, m1.w), fmaxf(m2.w, m3.w));
        const float inv = 1.0f / (float)CC;
        a.x = (a0.x + a1.x + a2.x + a3.x) * inv;
        a.y = (a0.y + a1.y + a2.y + a3.y) * inv;
        a.z = (a0.z + a1.z + a2.z + a3.z) * inv;
        a.w = (a0.w + a1.w + a2.w + a3.w) * inv;
        ((float4*)pmax)[gpos]  = m;
        ((float4*)pmean)[gpos] = a;
    }
}

// Kernel 2: 7x7 conv (2 in-ch) + bias + BN + sigmoid -> att. Unchanged.
__global__ __launch_bounds__(256) void conv_kernel(const float* __restrict__ pmax,
                                                   const float* __restrict__ pmean,
                                                   const float* __restrict__ cw,
                                                   const float* __restrict__ cb,
                                                   const float* __restrict__ g,
                                                   const float* __restrict__ be,
                                                   const float* __restrict__ mu,
                                                   const float* __restrict__ var,
                                                   float* __restrict__ att) {
    __shared__ float w[98];
    __shared__ float sc[2];
    if (threadIdx.x < 98) w[threadIdx.x] = cw[threadIdx.x];
    if (threadIdx.x == 0) {
        float scale = g[0] * rsqrtf(var[0] + 1e-5f);
        sc[0] = scale;
        sc[1] = cb[0] * scale + be[0] - mu[0] * scale;
    }
    __syncthreads();

    int s  = blockIdx.x * 256 + threadIdx.x;
    int b  = s >> 14;
    int hw = s & (HWSZ - 1);
    int h  = hw >> 7;
    int ww = hw & 127;
    const float* pm = pmax  + (size_t)b * HWSZ;
    const float* pa = pmean + (size_t)b * HWSZ;

    float acc = 0.0f;
    #pragma unroll
    for (int kh = 0; kh < 7; ++kh) {
        int hh = h + kh - 3;
        if ((unsigned)hh < (unsigned)HH) {
            int rowoff = hh << 7;
            #pragma unroll
            for (int kw = 0; kw < 7; ++kw) {
                int wcol = ww + kw - 3;
                if ((unsigned)wcol < (unsigned)WW) {
                    int o = rowoff + wcol;
                    acc = fmaf(w[kh * 7 + kw],      pm[o], acc);
                    acc = fmaf(w[49 + kh * 7 + kw], pa[o], acc);
                }
            }
        }
    }
    float y = fmaf(acc, sc[0], sc[1]);
    att[s] = 1.0f / (1.0f + __expf(-y));
}

// Kernel 3: out = x * att. NT store for out (no L2/L3 allocate -> preserves
// x residency in Infinity Cache); NT load for x (dead after this read).
__global__ __launch_bounds__(256) void mul_kernel(const float* __restrict__ x,
                                                  const float* __restrict__ att,
                                                  float* __restrict__ out,
                                                  int total4) {
    int stride = gridDim.x * 256;
    const f32x4* xv = (const f32x4*)x;
    f32x4*       ov = (f32x4*)out;
    for (int i = blockIdx.x * 256 + threadIdx.x; i < total4; i += stride) {
        int p   = i >> 12;        // b*C + c
        int b   = p >> 8;         // / C
        int hw4 = i & (HW4 - 1);
        float4 a = ((const float4*)att)[(b << 12) + hw4];
        f32x4 v = __builtin_nontemporal_load(xv + i);
        v.x *= a.x; v.y *= a.y; v.z *= a.z; v.w *= a.w;
        __builtin_nontemporal_store(v, ov + i);
    }
}

extern "C" void kernel_launch(void* const* d_in, const int* in_sizes, int n_in,
                              void* d_out, int out_size, void* d_ws, size_t ws_size,
                              hipStream_t stream) {
    const float* x   = (const float*)d_in[0];
    const float* cw  = (const float*)d_in[1];
    const float* cb  = (const float*)d_in[2];
    const float* g   = (const float*)d_in[3];
    const float* be  = (const float*)d_in[4];
    const float* mu  = (const float*)d_in[5];
    const float* var = (const float*)d_in[6];
    float* out = (float*)d_out;

    float* pmax  = (float*)d_ws;
    float* pmean = pmax + BHW;
    float* att   = pmean + BHW;

    pool_kernel<<<BHW / 4 / 64, 256, 0, stream>>>(x, pmax, pmean);
    conv_kernel<<<BHW / 256, 256, 0, stream>>>(pmax, pmean, cw, cb, g, be, mu, var, att);
    mul_kernel<<<4096, 256, 0, stream>>>(x, att, out, TOTAL / 4);
}

// Round 4
// 148.590 us; speedup vs baseline: 1.1985x; 1.0206x over previous
//
#include <hip/hip_runtime.h>

// Problem constants: x [B=16, C=256, H=128, W=128] f32 (NCHW)
#define BB 16
#define CC 256
#define HH 128
#define WW 128
#define HWSZ (HH * WW)          // 16384
#define HW4 (HWSZ / 4)          // 4096 float4 per plane
#define BHW (BB * HWSZ)         // 262144
#define TOTAL (BB * CC * HWSZ)  // 67108864

typedef float f32x4 __attribute__((ext_vector_type(4)));

// Kernel 1: channel pool, C split 4-way within the block.
// Temporal loads on purpose: they leave x resident in Infinity Cache so the
// mul kernel's second read of x hits L3 instead of HBM.
__global__ __launch_bounds__(256) void pool_kernel(const float* __restrict__ x,
                                                   float* __restrict__ pmax,
                                                   float* __restrict__ pmean) {
    __shared__ float4 smax[256];
    __shared__ float4 ssum[256];
    int t     = threadIdx.x;
    int pos   = t & 63;
    int chunk = t >> 6;
    int gpos  = blockIdx.x * 64 + pos;
    int b     = gpos >> 12;
    int hw4   = gpos & (HW4 - 1);
    const float4* xb = (const float4*)x + ((size_t)b << 20) + ((size_t)chunk << 18) + hw4;

    float4 v = xb[0];
    float mx0 = v.x, mx1 = v.y, mx2 = v.z, mx3 = v.w;
    float s0 = v.x, s1 = v.y, s2 = v.z, s3 = v.w;
    #pragma unroll 8
    for (int c = 1; c < 64; ++c) {
        float4 u = xb[(size_t)c << 12];
        mx0 = fmaxf(mx0, u.x); s0 += u.x;
        mx1 = fmaxf(mx1, u.y); s1 += u.y;
        mx2 = fmaxf(mx2, u.z); s2 += u.z;
        mx3 = fmaxf(mx3, u.w); s3 += u.w;
    }
    smax[t] = make_float4(mx0, mx1, mx2, mx3);
    ssum[t] = make_float4(s0, s1, s2, s3);
    __syncthreads();

    if (t < 64) {
        float4 m0 = smax[t],       m1 = smax[t + 64],
               m2 = smax[t + 128], m3 = smax[t + 192];
        float4 a0 = ssum[t],       a1 = ssum[t + 64],
               a2 = ssum[t + 128], a3 = ssum[t + 192];
        float4 m, a;
        m.x = fmaxf(fmaxf(m0.x, m1.x), fmaxf(m2.x, m3.x));
        m.y = fmaxf(fmaxf(m0.y, m1.y), fmaxf(m2.y, m3.y));
        m.z = fmaxf(fmaxf(m0.z, m1.z), fmaxf(m2.z, m3.z));
        m.w = fmaxf(fmaxf(m0.w, m1.w), fmaxf(m2.w, m3.w));
        const float inv = 1.0f / (float)CC;
        a.x = (a0.x + a1.x + a2.x + a3.x) * inv;
        a.y = (a0.y + a1.y + a2.y + a3.y) * inv;
        a.z = (a0.z + a1.z + a2.z + a3.z) * inv;
        a.w = (a0.w + a1.w + a2.w + a3.w) * inv;
        ((float4*)pmax)[gpos]  = m;
        ((float4*)pmean)[gpos] = a;
    }
}

// Kernel 2: 7x7 conv (2 in-ch) + bias + BN + sigmoid -> att. Unchanged.
__global__ __launch_bounds__(256) void conv_kernel(const float* __restrict__ pmax,
                                                   const float* __restrict__ pmean,
                                                   const float* __restrict__ cw,
                                                   const float* __restrict__ cb,
                                                   const float* __restrict__ g,
                                                   const float* __restrict__ be,
                                                   const float* __restrict__ mu,
                                                   const float* __restrict__ var,
                                                   float* __restrict__ att) {
    __shared__ float w[98];
    __shared__ float sc[2];
    if (threadIdx.x < 98) w[threadIdx.x] = cw[threadIdx.x];
    if (threadIdx.x == 0) {
        float scale = g[0] * rsqrtf(var[0] + 1e-5f);
        sc[0] = scale;
        sc[1] = cb[0] * scale + be[0] - mu[0] * scale;
    }
    __syncthreads();

    int s  = blockIdx.x * 256 + threadIdx.x;
    int b  = s >> 14;
    int hw = s & (HWSZ - 1);
    int h  = hw >> 7;
    int ww = hw & 127;
    const float* pm = pmax  + (size_t)b * HWSZ;
    const float* pa = pmean + (size_t)b * HWSZ;

    float acc = 0.0f;
    #pragma unroll
    for (int kh = 0; kh < 7; ++kh) {
        int hh = h + kh - 3;
        if ((unsigned)hh < (unsigned)HH) {
            int rowoff = hh << 7;
            #pragma unroll
            for (int kw = 0; kw < 7; ++kw) {
                int wcol = ww + kw - 3;
                if ((unsigned)wcol < (unsigned)WW) {
                    int o = rowoff + wcol;
                    acc = fmaf(w[kh * 7 + kw],      pm[o], acc);
                    acc = fmaf(w[49 + kh * 7 + kw], pa[o], acc);
                }
            }
        }
    }
    float y = fmaf(acc, sc[0], sc[1]);
    att[s] = 1.0f / (1.0f + __expf(-y));
}

// Kernel 3: out = x * att. TEMPORAL x load (hits L3 lines left by pool);
// NT store for out (no L2/L3 allocate -> preserves x residency).
__global__ __launch_bounds__(256) void mul_kernel(const float* __restrict__ x,
                                                  const float* __restrict__ att,
                                                  float* __restrict__ out,
                                                  int total4) {
    int stride = gridDim.x * 256;
    const f32x4* xv = (const f32x4*)x;
    f32x4*       ov = (f32x4*)out;
    for (int i = blockIdx.x * 256 + threadIdx.x; i < total4; i += stride) {
        int p   = i >> 12;        // b*C + c
        int b   = p >> 8;         // / C
        int hw4 = i & (HW4 - 1);
        float4 a = ((const float4*)att)[(b << 12) + hw4];
        f32x4 v = xv[i];
        v.x *= a.x; v.y *= a.y; v.z *= a.z; v.w *= a.w;
        __builtin_nontemporal_store(v, ov + i);
    }
}

extern "C" void kernel_launch(void* const* d_in, const int* in_sizes, int n_in,
                              void* d_out, int out_size, void* d_ws, size_t ws_size,
                              hipStream_t stream) {
    const float* x   = (const float*)d_in[0];
    const float* cw  = (const float*)d_in[1];
    const float* cb  = (const float*)d_in[2];
    const float* g   = (const float*)d_in[3];
    const float* be  = (const float*)d_in[4];
    const float* mu  = (const float*)d_in[5];
    const float* var = (const float*)d_in[6];
    float* out = (float*)d_out;

    float* pmax  = (float*)d_ws;
    float* pmean = pmax + BHW;
    float* att   = pmean + BHW;

    pool_kernel<<<BHW / 4 / 64, 256, 0, stream>>>(x, pmax, pmean);
    conv_kernel<<<BHW / 256, 256, 0, stream>>>(pmax, pmean, cw, cb, g, be, mu, var, att);
    mul_kernel<<<4096, 256, 0, stream>>>(x, att, out, TOTAL / 4);
}